// Round 8
// baseline (765.375 us; speedup 1.0000x reference)
//
#include <hip/hip_runtime.h>
#include <stdint.h>

#define DEVI __device__ __forceinline__

typedef __attribute__((ext_vector_type(8))) short bf16x8;
typedef __attribute__((ext_vector_type(4))) float f32x4;

DEVI short tobf(float v){
  uint32_t u = __builtin_bit_cast(uint32_t, v);
  uint32_t r = (u + 0x7fffu + ((u >> 16) & 1u)) >> 16;
  return (short)(uint16_t)r;
}

DEVI float frombf(short s){
  uint32_t u = ((uint32_t)(uint16_t)s) << 16;
  return __builtin_bit_cast(float, u);
}

DEVI f32x4 mfma16(bf16x8 a, bf16x8 b, f32x4 c){
  return __builtin_amdgcn_mfma_f32_16x16x32_bf16(a, b, c, 0, 0, 0);
}

// ---------------- shared LN row routine (one wave = one row of 512) ----------
// x = in + in2? + resf? + resb?(bf16) + cb?
DEVI void ln_row_compute(const float* __restrict__ in, const float* __restrict__ in2,
                         const float* __restrict__ resf, const short* __restrict__ resb,
                         const float* __restrict__ cb,
                         const float* __restrict__ g, const float* __restrict__ be,
                         const float* __restrict__ gn, const float* __restrict__ bn,
                         float* __restrict__ outf, short* __restrict__ outb, int row)
{
  const int lane = threadIdx.x & 63;
  const size_t base = (size_t)row * 512 + lane * 8;
  const int col = lane * 8;
  f32x4 x0 = *(const f32x4*)(in + base);
  f32x4 x1 = *(const f32x4*)(in + base + 4);
  if (in2){
    f32x4 a0 = *(const f32x4*)(in2 + base), a1 = *(const f32x4*)(in2 + base + 4);
    x0 += a0; x1 += a1;
  }
  if (cb){
    f32x4 c0 = *(const f32x4*)(cb + col), c1 = *(const f32x4*)(cb + col + 4);
    x0 += c0; x1 += c1;
  }
  if (resf){
    f32x4 r0v = *(const f32x4*)(resf + base), r1v = *(const f32x4*)(resf + base + 4);
    x0 += r0v; x1 += r1v;
  }
  if (resb){
    bf16x8 rb = *(const bf16x8*)(resb + base);
    #pragma unroll
    for (int i = 0; i < 4; i++){ x0[i] += frombf(rb[i]); x1[i] += frombf(rb[i+4]); }
  }
  float s = x0[0]+x0[1]+x0[2]+x0[3]+x1[0]+x1[1]+x1[2]+x1[3];
  #pragma unroll
  for (int m = 1; m < 64; m <<= 1) s += __shfl_xor(s, m, 64);
  const float mu = s * (1.f/512.f);
  float vs = 0.f;
  #pragma unroll
  for (int i = 0; i < 4; i++){
    float d0 = x0[i]-mu; vs += d0*d0;
    float d1 = x1[i]-mu; vs += d1*d1;
  }
  #pragma unroll
  for (int m = 1; m < 64; m <<= 1) vs += __shfl_xor(vs, m, 64);
  const float rs = rsqrtf(vs * (1.f/512.f) + 1e-3f);
  f32x4 gv0 = *(const f32x4*)(g+col),  gv1 = *(const f32x4*)(g+col+4);
  f32x4 bv0 = *(const f32x4*)(be+col), bv1 = *(const f32x4*)(be+col+4);
  f32x4 y0, y1;
  #pragma unroll
  for (int i = 0; i < 4; i++){
    y0[i] = (x0[i]-mu)*rs*gv0[i] + bv0[i];
    y1[i] = (x1[i]-mu)*rs*gv1[i] + bv1[i];
  }
  if (outf){ *(f32x4*)(outf+base) = y0; *(f32x4*)(outf+base+4) = y1; }
  if (outb){
    f32x4 z0 = y0, z1 = y1;
    if (gn){   // second LN (next layer's input-LN) in-register
      float s2 = z0[0]+z0[1]+z0[2]+z0[3]+z1[0]+z1[1]+z1[2]+z1[3];
      #pragma unroll
      for (int m = 1; m < 64; m <<= 1) s2 += __shfl_xor(s2, m, 64);
      const float mu2 = s2 * (1.f/512.f);
      float v2 = 0.f;
      #pragma unroll
      for (int i = 0; i < 4; i++){
        float d0 = z0[i]-mu2; v2 += d0*d0;
        float d1 = z1[i]-mu2; v2 += d1*d1;
      }
      #pragma unroll
      for (int m = 1; m < 64; m <<= 1) v2 += __shfl_xor(v2, m, 64);
      const float rs2 = rsqrtf(v2 * (1.f/512.f) + 1e-3f);
      f32x4 gn0 = *(const f32x4*)(gn+col), gn1 = *(const f32x4*)(gn+col+4);
      f32x4 bn0 = *(const f32x4*)(bn+col), bn1 = *(const f32x4*)(bn+col+4);
      #pragma unroll
      for (int i = 0; i < 4; i++){
        z0[i] = (z0[i]-mu2)*rs2*gn0[i] + bn0[i];
        z1[i] = (z1[i]-mu2)*rs2*gn1[i] + bn1[i];
      }
    }
    bf16x8 ob;
    #pragma unroll
    for (int i = 0; i < 4; i++){ ob[i] = tobf(z0[i]); ob[i+4] = tobf(z1[i]); }
    *(bf16x8*)(outb + base) = ob;
  }
}

// ---------------- ALL weight transposes (4 layers) + initial input-LN --------
__global__ __launch_bounds__(256)
void transpose_all(const float* __restrict__ Wq, const float* __restrict__ Wk,
                   const float* __restrict__ Wv, const float* __restrict__ W1,
                   const float* __restrict__ W2,
                   short* __restrict__ WqkvT, short* __restrict__ W1T,
                   short* __restrict__ W2T,
                   const float* __restrict__ x_in, const float* __restrict__ gin,
                   const float* __restrict__ bin, short* __restrict__ xl)
{
  if (blockIdx.x >= 11264){
    const int row = ((blockIdx.x - 11264) << 2) + (threadIdx.x >> 6);
    ln_row_compute(x_in, nullptr, nullptr, nullptr, nullptr, gin, bin,
                   nullptr, nullptr, nullptr, xl, row);
    return;
  }
  __shared__ float tsh[32][33];
  const int l = blockIdx.x / 2816;
  const int t = blockIdx.x % 2816;
  const float* src; short* dst; int K, N, local;
  if (t < 768){
    const int m = t >> 8;
    src = (m==0 ? Wq : (m==1 ? Wk : Wv)) + (size_t)l*262144;
    dst = WqkvT + (size_t)l*786432 + m*262144; K = 512; N = 512; local = t & 255;
  } else if (t < 1792){
    src = W1 + (size_t)l*1048576; dst = W1T + (size_t)l*1048576;
    K = 512; N = 2048; local = t - 768;
  } else {
    src = W2 + (size_t)l*1048576; dst = W2T + (size_t)l*1048576;
    K = 2048; N = 512; local = t - 1792;
  }
  const int tnx = N >> 5;
  const int tc = (local % tnx) << 5, tr = (local / tnx) << 5;
  const int lr = threadIdx.x >> 5, lc = threadIdx.x & 31;
  #pragma unroll
  for (int i = 0; i < 32; i += 8)
    tsh[lr + i][lc] = src[(size_t)(tr + lr + i) * N + tc + lc];
  __syncthreads();
  #pragma unroll
  for (int i = 0; i < 32; i += 8)
    dst[(size_t)(tc + lr + i) * K + tr + lc] = tobf(tsh[lc][lr + i]);
}

// ---------------- standalone LN launches -------------------------------------
__global__ __launch_bounds__(256)
void ln_kernel(const float* __restrict__ in, const float* __restrict__ in2,
               const float* __restrict__ resf, const short* __restrict__ resb,
               const float* __restrict__ cb,
               const float* __restrict__ g, const float* __restrict__ be,
               const float* __restrict__ gn, const float* __restrict__ bn,
               float* __restrict__ outf, short* __restrict__ outb)
{
  const int row = (blockIdx.x << 2) + (threadIdx.x >> 6);
  ln_row_compute(in, in2, resf, resb, cb, g, be, gn, bn, outf, outb, row);
}

// ---------------- bf16 MFMA GEMM, DIRECT-FROM-GLOBAL (no LDS, no barriers) ---
// A [M,K], BT [N,K] row-major, both L2-resident. 64x(32*BJ) block tile,
// 4 waves as 2M x 2N, per-wave 32x(16*BJ) via acc[2][BJ]. Fragment loads
// straight from global: wave reads 16 rows x 64B contiguous per load.
// MODE 0: +bias (3-section), bf16 row-major out, ld=N
// MODE 1: +bias, ReLU, bf16 out, ld=N
// MODE 3: f32 partial out (no bias) to out0 + z*M*N (split-K via gridDim.z)
template<int MODE, int BJ>
__global__ __launch_bounds__(256)
void gemm_bt(const short* __restrict__ A, const short* __restrict__ BT,
             int N, int K, int Ks,
             const float* __restrict__ b0, const float* __restrict__ b1p,
             const float* __restrict__ b2p, void* __restrict__ out0)
{
  constexpr int NTILE = 32*BJ;
  const int tid = threadIdx.x;
  const int wid = tid >> 6, lane = tid & 63;
  const int l15 = lane & 15, g4 = lane >> 4;
  const int nbn = N / NTILE;
  // bijective XCD-chunk swizzle (gridDim.x % 8 == 0 for all our grids)
  const int cpx = gridDim.x >> 3;
  int bid = blockIdx.x;
  bid = (bid & 7) * cpx + (bid >> 3);
  const int bm = bid / nbn, bn = bid % nbn;
  const int m0 = bm << 6, n0 = bn * NTILE;
  const int kofs = blockIdx.z * Ks;
  const int wr = wid & 1, wc = wid >> 1;

  // per-fragment global base pointers (row fixed per lane, k advances)
  const short* ap[2]; const short* bp[BJ];
  #pragma unroll
  for (int i = 0; i < 2; i++)
    ap[i] = A + (size_t)(m0 + wr*32 + i*16 + l15) * K + kofs + g4*8;
  #pragma unroll
  for (int j = 0; j < BJ; j++)
    bp[j] = BT + (size_t)(n0 + wc*16*BJ + j*16 + l15) * K + kofs + g4*8;

  f32x4 acc[2][BJ] = {};
  const int nkt = Ks >> 5;   // one mfma16 fragment covers K=32

  #pragma unroll 8
  for (int kt = 0; kt < nkt; ++kt){
    const int ko = kt << 5;
    bf16x8 af[2], bf[BJ];
    #pragma unroll
    for (int i = 0; i < 2; i++)  af[i] = *(const bf16x8*)(ap[i] + ko);
    #pragma unroll
    for (int j = 0; j < BJ; j++) bf[j] = *(const bf16x8*)(bp[j] + ko);
    #pragma unroll
    for (int i = 0; i < 2; i++)
      #pragma unroll
      for (int j = 0; j < BJ; j++)
        acc[i][j] = mfma16(af[i], bf[j], acc[i][j]);
  }

  // epilogue: D layout col=lane&15, row=(lane>>4)*4+reg
  const int r0 = m0 + wr*32 + g4*4;
  const int cc0 = n0 + wc*16*BJ + l15;
  #pragma unroll
  for (int j = 0; j < BJ; j++){
    const int gc = cc0 + j*16;
    if (MODE == 0){
      const float bi = gc < 512 ? b0[gc] : (gc < 1024 ? b1p[gc-512] : b2p[gc-1024]);
      short* ob = (short*)out0;
      #pragma unroll
      for (int i = 0; i < 2; i++)
        #pragma unroll
        for (int r = 0; r < 4; r++){
          const int grow = r0 + i*16 + r;
          ob[(size_t)grow * N + gc] = tobf(acc[i][j][r] + bi);
        }
    } else if (MODE == 1){
      const float bi = b0[gc];
      short* ob = (short*)out0;
      #pragma unroll
      for (int i = 0; i < 2; i++)
        #pragma unroll
        for (int r = 0; r < 4; r++){
          const int grow = r0 + i*16 + r;
          float v = acc[i][j][r] + bi;
          v = fmaxf(v, 0.f);
          ob[(size_t)grow * N + gc] = tobf(v);
        }
    } else {
      float* ob = (float*)out0 + (size_t)blockIdx.z * 2097152;
      #pragma unroll
      for (int i = 0; i < 2; i++)
        #pragma unroll
        for (int r = 0; r < 4; r++){
          const int grow = r0 + i*16 + r;
          ob[(size_t)grow * N + gc] = acc[i][j][r];
        }
    }
  }
}

// ---------------- unified banded chunk attention (+fused residual add) -------
// qkv row-major [B*S, 1536]: cols 0-511 Q, 512-1023 K, 1024-1535 V
__global__ __launch_bounds__(256)
void attn_kernel(const short* __restrict__ qkv, float* __restrict__ attnO,
                 const float* __restrict__ resid)
{
  constexpr int NT = 14, NK2 = 7, VS = 232, LDQ = 1536;
  __shared__ __align__(16) short Vt[64*VS];
  __shared__ __align__(16) short Pl[4][16*VS];
  const int c = blockIdx.x, h = blockIdx.y, b = blockIdx.z;
  const int kb0 = 64*c - 128;
  const size_t rowbase = (size_t)b*2048;
  const short* Q     = qkv + (rowbase + 64*c)*LDQ + h*64;
  const short* Kbase = qkv + rowbase*LDQ + 512  + h*64;
  const short* Vbase = qkv + rowbase*LDQ + 1024 + h*64;
  const int tid = threadIdx.x, wid = tid >> 6, lane = tid & 63;
  const int l15 = lane & 15, g4 = lane >> 4;

  // stage V transposed: Vt[d][t16+r] = V[kb0+t*16+r][d]; invalid tiles -> 0
  for (int idx = tid; idx < NT*16*64; idx += 256){
    const int t = idx >> 10, r = (idx >> 6) & 15, d = idx & 63;
    const int kb = kb0 + t*16;
    short v = 0;
    if (kb >= 0 && kb + 16 <= 2048) v = Vbase[(size_t)(kb + r)*LDQ + d];
    Vt[d*VS + t*16 + r] = v;
  }

  const short* qr = Q + (wid*16 + l15)*LDQ + g4*8;
  const bf16x8 aq0 = *(const bf16x8*)qr;
  const bf16x8 aq1 = *(const bf16x8*)(qr + 32);

  f32x4 sf[NT];
  #pragma unroll
  for (int t = 0; t < NT; t++){
    const int kb = kb0 + t*16;
    if (kb >= 0 && kb + 16 <= 2048){
      const short* kr = Kbase + (size_t)(kb + l15)*LDQ + g4*8;
      const bf16x8 k0 = *(const bf16x8*)kr;
      const bf16x8 k1 = *(const bf16x8*)(kr + 32);
      f32x4 z = {0.f,0.f,0.f,0.f};
      z = mfma16(aq0, k0, z);
      z = mfma16(aq1, k1, z);
      sf[t] = z;
    } else {
      sf[t] = (f32x4){-1e9f,-1e9f,-1e9f,-1e9f};
    }
  }

  float mx[4] = {-1e30f,-1e30f,-1e30f,-1e30f};
  #pragma unroll
  for (int t = 0; t < NT; t++)
    #pragma unroll
    for (int r = 0; r < 4; r++) mx[r] = fmaxf(mx[r], sf[t][r]);
  #pragma unroll
  for (int m = 1; m < 16; m <<= 1)
    #pragma unroll
    for (int r = 0; r < 4; r++) mx[r] = fmaxf(mx[r], __shfl_xor(mx[r], m, 64));

  float sum[4] = {0.f,0.f,0.f,0.f};
  #pragma unroll
  for (int t = 0; t < NT; t++)
    #pragma unroll
    for (int r = 0; r < 4; r++){
      const float p = __expf((sf[t][r] - mx[r]) * 0.125f);
      sf[t][r] = p; sum[r] += p;
    }
  #pragma unroll
  for (int m = 1; m < 16; m <<= 1)
    #pragma unroll
    for (int r = 0; r < 4; r++) sum[r] += __shfl_xor(sum[r], m, 64);
  float inv[4];
  #pragma unroll
  for (int r = 0; r < 4; r++) inv[r] = 1.f / sum[r];

  short* Pw = Pl[wid];
  #pragma unroll
  for (int t = 0; t < NT; t++)
    #pragma unroll
    for (int r = 0; r < 4; r++)
      Pw[(g4*4 + r)*VS + t*16 + l15] = tobf(sf[t][r]);

  __syncthreads();

  f32x4 ao[4] = {};
  #pragma unroll
  for (int ks = 0; ks < NK2; ks++){
    const bf16x8 pa = *(const bf16x8*)&Pw[l15*VS + ks*32 + g4*8];
    #pragma unroll
    for (int ni = 0; ni < 4; ni++){
      const bf16x8 vb = *(const bf16x8*)&Vt[(ni*16 + l15)*VS + ks*32 + g4*8];
      ao[ni] = mfma16(pa, vb, ao[ni]);
    }
  }

  const int orow = 64*c + wid*16 + g4*4;
  const size_t obase = ((size_t)b*2048 + orow)*512 + h*64;
  float* ob = attnO + obase;
  const float* rb = resid + obase;
  #pragma unroll
  for (int ni = 0; ni < 4; ni++)
    #pragma unroll
    for (int r = 0; r < 4; r++)
      ob[(size_t)r*512 + ni*16 + l15] = ao[ni][r] * inv[r] + rb[(size_t)r*512 + ni*16 + l15];
}

// ---------------- host launcher ----------------------------------------------
extern "C" void kernel_launch(void* const* d_in, const int* in_sizes, int n_in,
                              void* d_out, int out_size, void* d_ws, size_t ws_size,
                              hipStream_t stream)
{
  const float* x_in = (const float*)d_in[0];
  const float* Wq = (const float*)d_in[2];
  const float* bq = (const float*)d_in[3];
  const float* Wk = (const float*)d_in[4];
  const float* bk = (const float*)d_in[5];
  const float* Wv = (const float*)d_in[6];
  const float* bv = (const float*)d_in[7];
  const float* W1 = (const float*)d_in[8];
  const float* b1 = (const float*)d_in[9];
  const float* W2 = (const float*)d_in[10];
  const float* b2 = (const float*)d_in[11];
  const float* gin = (const float*)d_in[12];
  const float* bin = (const float*)d_in[13];
  const float* g1  = (const float*)d_in[14];
  const float* be1 = (const float*)d_in[15];
  const float* g2  = (const float*)d_in[16];
  const float* be2 = (const float*)d_in[17];

  char* ws = (char*)d_ws;
  size_t o = 0;
  float* xbuf  = (float*)(ws + o); o += (size_t)4096*512*4;   // layer input x (f32)
  short* xl    = (short*)(ws + o); o += (size_t)4096*512*2;   // bf16 LN output (GEMM A / residual)
  short* qkv   = (short*)(ws + o); o += (size_t)4096*1536*2;  // row-major QKV
  float* attnO = (float*)(ws + o); o += (size_t)4096*512*4;   // attn out + x
  short* h1    = (short*)(ws + o); o += (size_t)4096*2048*2;  // FFN hidden
  float* pbuf  = (float*)(ws + o); o += (size_t)2*4096*512*4; // FFN2 split-K partials
  short* WqkvT = (short*)(ws + o); o += (size_t)4*1536*512*2;
  short* W1T   = (short*)(ws + o); o += (size_t)4*2048*512*2;
  short* W2T   = (short*)(ws + o); o += (size_t)4*512*2048*2;

  transpose_all<<<12288,256,0,stream>>>(Wq, Wk, Wv, W1, W2, WqkvT, W1T, W2T,
                                        x_in, gin, bin, xl);

  const float* xcur = x_in;
  for (int l = 0; l < 4; l++){
    gemm_bt<0,3><<<1024,256,0,stream>>>(xl, WqkvT + (size_t)l*786432, 1536, 512, 512,
                                        bq + l*512, bk + l*512, bv + l*512, qkv);
    attn_kernel<<<dim3(32,8,2),256,0,stream>>>(qkv, attnO, xcur);
    // ln1: xl = bf16 LN(attnO)  (serves as FFN1 input AND ln2 residual)
    ln_kernel<<<1024,256,0,stream>>>(attnO, nullptr, nullptr, nullptr, nullptr,
                                     g1 + l*512, be1 + l*512, nullptr, nullptr,
                                     nullptr, xl);
    gemm_bt<1,4><<<1024,256,0,stream>>>(xl, W1T + (size_t)l*1048576, 2048, 512, 512,
                                        b1 + l*2048, nullptr, nullptr, h1);
    gemm_bt<3,2><<<dim3(512,1,2),256,0,stream>>>(h1, W2T + (size_t)l*1048576, 512, 2048, 1024,
                                                 nullptr, nullptr, nullptr, pbuf);
    if (l < 3){
      ln_kernel<<<1024,256,0,stream>>>(pbuf, pbuf + 2097152, nullptr, xl, b2 + l*512,
                                       g2 + l*512, be2 + l*512,
                                       gin + (l+1)*512, bin + (l+1)*512,
                                       xbuf, xl);
      xcur = xbuf;
    } else {
      ln_kernel<<<1024,256,0,stream>>>(pbuf, pbuf + 2097152, nullptr, xl, b2 + l*512,
                                       g2 + l*512, be2 + l*512,
                                       nullptr, nullptr, (float*)d_out, nullptr);
    }
  }
}

// Round 9
// 297.872 us; speedup vs baseline: 2.5695x; 2.5695x over previous
//
#include <hip/hip_runtime.h>
#include <stdint.h>

#define DEVI __device__ __forceinline__

typedef __attribute__((ext_vector_type(8))) short bf16x8;
typedef __attribute__((ext_vector_type(4))) float f32x4;

DEVI short tobf(float v){
  uint32_t u = __builtin_bit_cast(uint32_t, v);
  uint32_t r = (u + 0x7fffu + ((u >> 16) & 1u)) >> 16;
  return (short)(uint16_t)r;
}

DEVI float frombf(short s){
  uint32_t u = ((uint32_t)(uint16_t)s) << 16;
  return __builtin_bit_cast(float, u);
}

DEVI f32x4 mfma16(bf16x8 a, bf16x8 b, f32x4 c){
  return __builtin_amdgcn_mfma_f32_16x16x32_bf16(a, b, c, 0, 0, 0);
}

DEVI void async16(const void* g, void* lds_uniform){
  __builtin_amdgcn_global_load_lds(
      (const __attribute__((address_space(1))) unsigned int*)g,
      (__attribute__((address_space(3))) unsigned int*)lds_uniform,
      16, 0, 0);
}

// ---------------- shared LN row routine (one wave = one row of 512) ----------
// x = in + in2? + resf? + resb?(bf16) + cb?
DEVI void ln_row_compute(const float* __restrict__ in, const float* __restrict__ in2,
                         const float* __restrict__ resf, const short* __restrict__ resb,
                         const float* __restrict__ cb,
                         const float* __restrict__ g, const float* __restrict__ be,
                         const float* __restrict__ gn, const float* __restrict__ bn,
                         float* __restrict__ outf, short* __restrict__ outb, int row)
{
  const int lane = threadIdx.x & 63;
  const size_t base = (size_t)row * 512 + lane * 8;
  const int col = lane * 8;
  f32x4 x0 = *(const f32x4*)(in + base);
  f32x4 x1 = *(const f32x4*)(in + base + 4);
  if (in2){
    f32x4 a0 = *(const f32x4*)(in2 + base), a1 = *(const f32x4*)(in2 + base + 4);
    x0 += a0; x1 += a1;
  }
  if (cb){
    f32x4 c0 = *(const f32x4*)(cb + col), c1 = *(const f32x4*)(cb + col + 4);
    x0 += c0; x1 += c1;
  }
  if (resf){
    f32x4 r0v = *(const f32x4*)(resf + base), r1v = *(const f32x4*)(resf + base + 4);
    x0 += r0v; x1 += r1v;
  }
  if (resb){
    bf16x8 rb = *(const bf16x8*)(resb + base);
    #pragma unroll
    for (int i = 0; i < 4; i++){ x0[i] += frombf(rb[i]); x1[i] += frombf(rb[i+4]); }
  }
  float s = x0[0]+x0[1]+x0[2]+x0[3]+x1[0]+x1[1]+x1[2]+x1[3];
  #pragma unroll
  for (int m = 1; m < 64; m <<= 1) s += __shfl_xor(s, m, 64);
  const float mu = s * (1.f/512.f);
  float vs = 0.f;
  #pragma unroll
  for (int i = 0; i < 4; i++){
    float d0 = x0[i]-mu; vs += d0*d0;
    float d1 = x1[i]-mu; vs += d1*d1;
  }
  #pragma unroll
  for (int m = 1; m < 64; m <<= 1) vs += __shfl_xor(vs, m, 64);
  const float rs = rsqrtf(vs * (1.f/512.f) + 1e-3f);
  f32x4 gv0 = *(const f32x4*)(g+col),  gv1 = *(const f32x4*)(g+col+4);
  f32x4 bv0 = *(const f32x4*)(be+col), bv1 = *(const f32x4*)(be+col+4);
  f32x4 y0, y1;
  #pragma unroll
  for (int i = 0; i < 4; i++){
    y0[i] = (x0[i]-mu)*rs*gv0[i] + bv0[i];
    y1[i] = (x1[i]-mu)*rs*gv1[i] + bv1[i];
  }
  if (outf){ *(f32x4*)(outf+base) = y0; *(f32x4*)(outf+base+4) = y1; }
  if (outb){
    f32x4 z0 = y0, z1 = y1;
    if (gn){   // second LN (next layer's input-LN) in-register
      float s2 = z0[0]+z0[1]+z0[2]+z0[3]+z1[0]+z1[1]+z1[2]+z1[3];
      #pragma unroll
      for (int m = 1; m < 64; m <<= 1) s2 += __shfl_xor(s2, m, 64);
      const float mu2 = s2 * (1.f/512.f);
      float v2 = 0.f;
      #pragma unroll
      for (int i = 0; i < 4; i++){
        float d0 = z0[i]-mu2; v2 += d0*d0;
        float d1 = z1[i]-mu2; v2 += d1*d1;
      }
      #pragma unroll
      for (int m = 1; m < 64; m <<= 1) v2 += __shfl_xor(v2, m, 64);
      const float rs2 = rsqrtf(v2 * (1.f/512.f) + 1e-3f);
      f32x4 gn0 = *(const f32x4*)(gn+col), gn1 = *(const f32x4*)(gn+col+4);
      f32x4 bn0 = *(const f32x4*)(bn+col), bn1 = *(const f32x4*)(bn+col+4);
      #pragma unroll
      for (int i = 0; i < 4; i++){
        z0[i] = (z0[i]-mu2)*rs2*gn0[i] + bn0[i];
        z1[i] = (z1[i]-mu2)*rs2*gn1[i] + bn1[i];
      }
    }
    bf16x8 ob;
    #pragma unroll
    for (int i = 0; i < 4; i++){ ob[i] = tobf(z0[i]); ob[i+4] = tobf(z1[i]); }
    *(bf16x8*)(outb + base) = ob;
  }
}

// ---------------- ALL weight transposes (4 layers) + initial input-LN --------
__global__ __launch_bounds__(256)
void transpose_all(const float* __restrict__ Wq, const float* __restrict__ Wk,
                   const float* __restrict__ Wv, const float* __restrict__ W1,
                   const float* __restrict__ W2,
                   short* __restrict__ WqkvT, short* __restrict__ W1T,
                   short* __restrict__ W2T,
                   const float* __restrict__ x_in, const float* __restrict__ gin,
                   const float* __restrict__ bin, short* __restrict__ xl)
{
  if (blockIdx.x >= 11264){
    const int row = ((blockIdx.x - 11264) << 2) + (threadIdx.x >> 6);
    ln_row_compute(x_in, nullptr, nullptr, nullptr, nullptr, gin, bin,
                   nullptr, nullptr, nullptr, xl, row);
    return;
  }
  __shared__ float tsh[32][33];
  const int l = blockIdx.x / 2816;
  const int t = blockIdx.x % 2816;
  const float* src; short* dst; int K, N, local;
  if (t < 768){
    const int m = t >> 8;
    src = (m==0 ? Wq : (m==1 ? Wk : Wv)) + (size_t)l*262144;
    dst = WqkvT + (size_t)l*786432 + m*262144; K = 512; N = 512; local = t & 255;
  } else if (t < 1792){
    src = W1 + (size_t)l*1048576; dst = W1T + (size_t)l*1048576;
    K = 512; N = 2048; local = t - 768;
  } else {
    src = W2 + (size_t)l*1048576; dst = W2T + (size_t)l*1048576;
    K = 2048; N = 512; local = t - 1792;
  }
  const int tnx = N >> 5;
  const int tc = (local % tnx) << 5, tr = (local / tnx) << 5;
  const int lr = threadIdx.x >> 5, lc = threadIdx.x & 31;
  #pragma unroll
  for (int i = 0; i < 32; i += 8)
    tsh[lr + i][lc] = src[(size_t)(tr + lr + i) * N + tc + lc];
  __syncthreads();
  #pragma unroll
  for (int i = 0; i < 32; i += 8)
    dst[(size_t)(tc + lr + i) * K + tr + lc] = tobf(tsh[lc][lr + i]);
}

// ---------------- standalone LN launches -------------------------------------
__global__ __launch_bounds__(256)
void ln_kernel(const float* __restrict__ in, const float* __restrict__ in2,
               const float* __restrict__ resf, const short* __restrict__ resb,
               const float* __restrict__ cb,
               const float* __restrict__ g, const float* __restrict__ be,
               const float* __restrict__ gn, const float* __restrict__ bn,
               float* __restrict__ outf, short* __restrict__ outb)
{
  const int row = (blockIdx.x << 2) + (threadIdx.x >> 6);
  ln_row_compute(in, in2, resf, resb, cb, g, be, gn, bn, outf, outb, row);
}

// ---------------- bf16 MFMA GEMM, BT input ([N][K]), 64x(32*BJ) tile ---------
// LDS-staged (r7-proven loop), templated BK (64 or 128).
// MODE 0: +bias (3-section), bf16 row-major out, ld=N
// MODE 1: +bias, ReLU, bf16 out, ld=N
// MODE 3: +bias b0, f32 out, ld=N
template<int MODE, int BJ, int BK>
__global__ __launch_bounds__(256)
void gemm_bt(const short* __restrict__ A, const short* __restrict__ BT,
             int N, int K,
             const float* __restrict__ b0, const float* __restrict__ b1p,
             const float* __restrict__ b2p, void* __restrict__ out0)
{
  constexpr int NTILE = 32*BJ;
  constexpr int UPR = BK/8;           // 16B units per LDS row
  constexpr int AU = 64*UPR/256;      // async16 per thread (A)
  constexpr int BU = NTILE*UPR/256;   // async16 per thread (B)
  __shared__ __align__(16) short Ash[64*BK];
  __shared__ __align__(16) short Bsh[NTILE*BK];
  const int tid = threadIdx.x;
  const int wid = tid >> 6, lane = tid & 63;
  const int l15 = lane & 15, g4 = lane >> 4;
  const int nbn = N / NTILE;
  // bijective XCD-chunk swizzle (gridDim.x % 8 == 0 for all our grids)
  const int cpx = gridDim.x >> 3;
  int bid = blockIdx.x;
  bid = (bid & 7) * cpx + (bid >> 3);
  const int bm = bid / nbn, bn = bid % nbn;
  const int m0 = bm << 6, n0 = bn * NTILE;

  // staging: unit u = 16B; row = u/UPR; physical slot u%UPR holds logical
  // slot (u%UPR)^(row&(UPR-1)) (XOR swizzle, inverted on the read side)
  const short* aP[AU]; const short* bP[BU];
  #pragma unroll
  for (int p = 0; p < AU; p++){
    int u = p*256 + tid, row = u / UPR, sl = (u % UPR) ^ (row & (UPR-1));
    aP[p] = A + (size_t)(m0 + row) * K + sl * 8;
  }
  #pragma unroll
  for (int p = 0; p < BU; p++){
    int u = p*256 + tid, row = u / UPR, sl = (u % UPR) ^ (row & (UPR-1));
    bP[p] = BT + (size_t)(n0 + row) * K + sl * 8;
  }
  char* ldsA = (char*)Ash;
  char* ldsB = (char*)Bsh;

  f32x4 acc[2][BJ] = {};
  const int wr = wid & 1, wc = wid >> 1;
  const int nkt = K / BK;

  for (int kt = 0; kt < nkt; ++kt){
    const int k0 = kt * BK;
    #pragma unroll
    for (int p = 0; p < AU; p++)
      async16(aP[p] + k0, ldsA + (p*256 + wid*64) * 16);
    #pragma unroll
    for (int p = 0; p < BU; p++)
      async16(bP[p] + k0, ldsB + (p*256 + wid*64) * 16);
    __syncthreads();
    #pragma unroll
    for (int ks = 0; ks < BK/32; ++ks){
      bf16x8 af[2], bfm[BJ];
      #pragma unroll
      for (int i = 0; i < 2; i++){
        const int ar = wr*32 + i*16 + l15;
        af[i] = *(const bf16x8*)&ldsA[ar*(2*BK) + (((ks<<2)+g4) ^ (ar&(UPR-1)))*16];
      }
      #pragma unroll
      for (int j = 0; j < BJ; j++){
        const int br = wc*(16*BJ) + j*16 + l15;
        bfm[j] = *(const bf16x8*)&ldsB[br*(2*BK) + (((ks<<2)+g4) ^ (br&(UPR-1)))*16];
      }
      #pragma unroll
      for (int i = 0; i < 2; i++)
        #pragma unroll
        for (int j = 0; j < BJ; j++)
          acc[i][j] = mfma16(af[i], bfm[j], acc[i][j]);
    }
    __syncthreads();
  }

  // epilogue: D layout col=lane&15, row=(lane>>4)*4+reg
  const int r0 = m0 + wr*32 + g4*4;
  const int cc0 = n0 + wc*16*BJ + l15;
  #pragma unroll
  for (int j = 0; j < BJ; j++){
    const int gc = cc0 + j*16;
    if (MODE == 0){
      const float bi = gc < 512 ? b0[gc] : (gc < 1024 ? b1p[gc-512] : b2p[gc-1024]);
      short* ob = (short*)out0;
      #pragma unroll
      for (int i = 0; i < 2; i++)
        #pragma unroll
        for (int r = 0; r < 4; r++){
          const int grow = r0 + i*16 + r;
          ob[(size_t)grow * N + gc] = tobf(acc[i][j][r] + bi);
        }
    } else if (MODE == 1){
      const float bi = b0[gc];
      short* ob = (short*)out0;
      #pragma unroll
      for (int i = 0; i < 2; i++)
        #pragma unroll
        for (int r = 0; r < 4; r++){
          const int grow = r0 + i*16 + r;
          float v = acc[i][j][r] + bi;
          v = fmaxf(v, 0.f);
          ob[(size_t)grow * N + gc] = tobf(v);
        }
    } else {
      const float bi = b0[gc];
      float* ob = (float*)out0;
      #pragma unroll
      for (int i = 0; i < 2; i++)
        #pragma unroll
        for (int r = 0; r < 4; r++){
          const int grow = r0 + i*16 + r;
          ob[(size_t)grow * N + gc] = acc[i][j][r] + bi;
        }
    }
  }
}

// ---------------- unified banded chunk attention (+fused residual add) -------
// qkv row-major [B*S, 1536]: cols 0-511 Q, 512-1023 K, 1024-1535 V
__global__ __launch_bounds__(256)
void attn_kernel(const short* __restrict__ qkv, float* __restrict__ attnO,
                 const float* __restrict__ resid)
{
  constexpr int NT = 14, NK2 = 7, VS = 232, LDQ = 1536;
  __shared__ __align__(16) short Vt[64*VS];
  __shared__ __align__(16) short Pl[4][16*VS];
  const int c = blockIdx.x, h = blockIdx.y, b = blockIdx.z;
  const int kb0 = 64*c - 128;
  const size_t rowbase = (size_t)b*2048;
  const short* Q     = qkv + (rowbase + 64*c)*LDQ + h*64;
  const short* Kbase = qkv + rowbase*LDQ + 512  + h*64;
  const short* Vbase = qkv + rowbase*LDQ + 1024 + h*64;
  const int tid = threadIdx.x, wid = tid >> 6, lane = tid & 63;
  const int l15 = lane & 15, g4 = lane >> 4;

  // stage V transposed: vectorized global load (bf16x8 along d), scalar scatter
  for (int idx = tid; idx < NT*16*8; idx += 256){
    const int t = idx >> 7, rem = idx & 127;
    const int r = rem >> 3, d8 = (rem & 7) << 3;
    const int kb = kb0 + t*16;
    bf16x8 v = {0,0,0,0,0,0,0,0};
    if (kb >= 0 && kb + 16 <= 2048)
      v = *(const bf16x8*)(Vbase + (size_t)(kb + r)*LDQ + d8);
    short* dst = &Vt[d8*VS + t*16 + r];
    #pragma unroll
    for (int e = 0; e < 8; e++) dst[e*VS] = v[e];
  }

  const short* qr = Q + (wid*16 + l15)*LDQ + g4*8;
  const bf16x8 aq0 = *(const bf16x8*)qr;
  const bf16x8 aq1 = *(const bf16x8*)(qr + 32);

  f32x4 sf[NT];
  #pragma unroll
  for (int t = 0; t < NT; t++){
    const int kb = kb0 + t*16;
    if (kb >= 0 && kb + 16 <= 2048){
      const short* kr = Kbase + (size_t)(kb + l15)*LDQ + g4*8;
      const bf16x8 k0 = *(const bf16x8*)kr;
      const bf16x8 k1 = *(const bf16x8*)(kr + 32);
      f32x4 z = {0.f,0.f,0.f,0.f};
      z = mfma16(aq0, k0, z);
      z = mfma16(aq1, k1, z);
      sf[t] = z;
    } else {
      sf[t] = (f32x4){-1e9f,-1e9f,-1e9f,-1e9f};
    }
  }

  float mx[4] = {-1e30f,-1e30f,-1e30f,-1e30f};
  #pragma unroll
  for (int t = 0; t < NT; t++)
    #pragma unroll
    for (int r = 0; r < 4; r++) mx[r] = fmaxf(mx[r], sf[t][r]);
  #pragma unroll
  for (int m = 1; m < 16; m <<= 1)
    #pragma unroll
    for (int r = 0; r < 4; r++) mx[r] = fmaxf(mx[r], __shfl_xor(mx[r], m, 64));

  float sum[4] = {0.f,0.f,0.f,0.f};
  #pragma unroll
  for (int t = 0; t < NT; t++)
    #pragma unroll
    for (int r = 0; r < 4; r++){
      const float p = __expf((sf[t][r] - mx[r]) * 0.125f);
      sf[t][r] = p; sum[r] += p;
    }
  #pragma unroll
  for (int m = 1; m < 16; m <<= 1)
    #pragma unroll
    for (int r = 0; r < 4; r++) sum[r] += __shfl_xor(sum[r], m, 64);
  float inv[4];
  #pragma unroll
  for (int r = 0; r < 4; r++) inv[r] = 1.f / sum[r];

  short* Pw = Pl[wid];
  #pragma unroll
  for (int t = 0; t < NT; t++)
    #pragma unroll
    for (int r = 0; r < 4; r++)
      Pw[(g4*4 + r)*VS + t*16 + l15] = tobf(sf[t][r]);

  __syncthreads();

  f32x4 ao[4] = {};
  #pragma unroll
  for (int ks = 0; ks < NK2; ks++){
    const bf16x8 pa = *(const bf16x8*)&Pw[l15*VS + ks*32 + g4*8];
    #pragma unroll
    for (int ni = 0; ni < 4; ni++){
      const bf16x8 vb = *(const bf16x8*)&Vt[(ni*16 + l15)*VS + ks*32 + g4*8];
      ao[ni] = mfma16(pa, vb, ao[ni]);
    }
  }

  const int orow = 64*c + wid*16 + g4*4;
  const size_t obase = ((size_t)b*2048 + orow)*512 + h*64;
  float* ob = attnO + obase;
  const float* rb = resid + obase;
  #pragma unroll
  for (int ni = 0; ni < 4; ni++)
    #pragma unroll
    for (int r = 0; r < 4; r++)
      ob[(size_t)r*512 + ni*16 + l15] = ao[ni][r] * inv[r] + rb[(size_t)r*512 + ni*16 + l15];
}

// ---------------- host launcher ----------------------------------------------
extern "C" void kernel_launch(void* const* d_in, const int* in_sizes, int n_in,
                              void* d_out, int out_size, void* d_ws, size_t ws_size,
                              hipStream_t stream)
{
  const float* x_in = (const float*)d_in[0];
  const float* Wq = (const float*)d_in[2];
  const float* bq = (const float*)d_in[3];
  const float* Wk = (const float*)d_in[4];
  const float* bk = (const float*)d_in[5];
  const float* Wv = (const float*)d_in[6];
  const float* bv = (const float*)d_in[7];
  const float* W1 = (const float*)d_in[8];
  const float* b1 = (const float*)d_in[9];
  const float* W2 = (const float*)d_in[10];
  const float* b2 = (const float*)d_in[11];
  const float* gin = (const float*)d_in[12];
  const float* bin = (const float*)d_in[13];
  const float* g1  = (const float*)d_in[14];
  const float* be1 = (const float*)d_in[15];
  const float* g2  = (const float*)d_in[16];
  const float* be2 = (const float*)d_in[17];

  char* ws = (char*)d_ws;
  size_t o = 0;
  float* xbuf  = (float*)(ws + o); o += (size_t)4096*512*4;   // layer input x (f32)
  short* xl    = (short*)(ws + o); o += (size_t)4096*512*2;   // bf16 LN output (GEMM A / residual)
  short* qkv   = (short*)(ws + o); o += (size_t)4096*1536*2;  // row-major QKV
  float* attnO = (float*)(ws + o); o += (size_t)4096*512*4;   // attn out + x
  short* h1    = (short*)(ws + o); o += (size_t)4096*2048*2;  // FFN hidden
  float* pbuf  = (float*)(ws + o); o += (size_t)4096*512*4;   // FFN2 out (f32, +bias)
  short* WqkvT = (short*)(ws + o); o += (size_t)4*1536*512*2;
  short* W1T   = (short*)(ws + o); o += (size_t)4*2048*512*2;
  short* W2T   = (short*)(ws + o); o += (size_t)4*512*2048*2;

  transpose_all<<<12288,256,0,stream>>>(Wq, Wk, Wv, W1, W2, WqkvT, W1T, W2T,
                                        x_in, gin, bin, xl);

  const float* xcur = x_in;
  for (int l = 0; l < 4; l++){
    gemm_bt<0,3,128><<<1024,256,0,stream>>>(xl, WqkvT + (size_t)l*786432, 1536, 512,
                                            bq + l*512, bk + l*512, bv + l*512, qkv);
    attn_kernel<<<dim3(32,8,2),256,0,stream>>>(qkv, attnO, xcur);
    // ln1: xl = bf16 LN(attnO)  (serves as FFN1 input AND ln2 residual)
    ln_kernel<<<1024,256,0,stream>>>(attnO, nullptr, nullptr, nullptr, nullptr,
                                     g1 + l*512, be1 + l*512, nullptr, nullptr,
                                     nullptr, xl);
    gemm_bt<1,4,64><<<1024,256,0,stream>>>(xl, W1T + (size_t)l*1048576, 2048, 512,
                                           b1 + l*2048, nullptr, nullptr, h1);
    gemm_bt<3,2,128><<<512,256,0,stream>>>(h1, W2T + (size_t)l*1048576, 512, 2048,
                                           b2 + l*512, nullptr, nullptr, pbuf);
    if (l < 3){
      ln_kernel<<<1024,256,0,stream>>>(pbuf, nullptr, nullptr, xl, nullptr,
                                       g2 + l*512, be2 + l*512,
                                       gin + (l+1)*512, bin + (l+1)*512,
                                       xbuf, xl);
      xcur = xbuf;
    } else {
      ln_kernel<<<1024,256,0,stream>>>(pbuf, nullptr, nullptr, xl, nullptr,
                                       g2 + l*512, be2 + l*512,
                                       nullptr, nullptr, (float*)d_out, nullptr);
    }
  }
}

// Round 10
// 292.718 us; speedup vs baseline: 2.6147x; 1.0176x over previous
//
#include <hip/hip_runtime.h>
#include <stdint.h>

#define DEVI __device__ __forceinline__

typedef __attribute__((ext_vector_type(8))) short bf16x8;
typedef __attribute__((ext_vector_type(4))) float f32x4;

DEVI short tobf(float v){
  uint32_t u = __builtin_bit_cast(uint32_t, v);
  uint32_t r = (u + 0x7fffu + ((u >> 16) & 1u)) >> 16;
  return (short)(uint16_t)r;
}

DEVI float frombf(short s){
  uint32_t u = ((uint32_t)(uint16_t)s) << 16;
  return __builtin_bit_cast(float, u);
}

DEVI f32x4 mfma16(bf16x8 a, bf16x8 b, f32x4 c){
  return __builtin_amdgcn_mfma_f32_16x16x32_bf16(a, b, c, 0, 0, 0);
}

DEVI void async16(const void* g, void* lds_uniform){
  __builtin_amdgcn_global_load_lds(
      (const __attribute__((address_space(1))) unsigned int*)g,
      (__attribute__((address_space(3))) unsigned int*)lds_uniform,
      16, 0, 0);
}

// ---------------- shared LN row routine (one wave = one row of 512) ----------
// x = (in | inb) + resf? + resb?(bf16)
DEVI void ln_row_compute(const float* __restrict__ in, const short* __restrict__ inb,
                         const float* __restrict__ resf, const short* __restrict__ resb,
                         const float* __restrict__ g, const float* __restrict__ be,
                         const float* __restrict__ gn, const float* __restrict__ bn,
                         float* __restrict__ outf, short* __restrict__ outb, int row)
{
  const int lane = threadIdx.x & 63;
  const size_t base = (size_t)row * 512 + lane * 8;
  const int col = lane * 8;
  f32x4 x0, x1;
  if (in){
    x0 = *(const f32x4*)(in + base);
    x1 = *(const f32x4*)(in + base + 4);
  } else {
    bf16x8 ib = *(const bf16x8*)(inb + base);
    #pragma unroll
    for (int i = 0; i < 4; i++){ x0[i] = frombf(ib[i]); x1[i] = frombf(ib[i+4]); }
  }
  if (resf){
    f32x4 r0v = *(const f32x4*)(resf + base), r1v = *(const f32x4*)(resf + base + 4);
    x0 += r0v; x1 += r1v;
  }
  if (resb){
    bf16x8 rb = *(const bf16x8*)(resb + base);
    #pragma unroll
    for (int i = 0; i < 4; i++){ x0[i] += frombf(rb[i]); x1[i] += frombf(rb[i+4]); }
  }
  float s = x0[0]+x0[1]+x0[2]+x0[3]+x1[0]+x1[1]+x1[2]+x1[3];
  #pragma unroll
  for (int m = 1; m < 64; m <<= 1) s += __shfl_xor(s, m, 64);
  const float mu = s * (1.f/512.f);
  float vs = 0.f;
  #pragma unroll
  for (int i = 0; i < 4; i++){
    float d0 = x0[i]-mu; vs += d0*d0;
    float d1 = x1[i]-mu; vs += d1*d1;
  }
  #pragma unroll
  for (int m = 1; m < 64; m <<= 1) vs += __shfl_xor(vs, m, 64);
  const float rs = rsqrtf(vs * (1.f/512.f) + 1e-3f);
  f32x4 gv0 = *(const f32x4*)(g+col),  gv1 = *(const f32x4*)(g+col+4);
  f32x4 bv0 = *(const f32x4*)(be+col), bv1 = *(const f32x4*)(be+col+4);
  f32x4 y0, y1;
  #pragma unroll
  for (int i = 0; i < 4; i++){
    y0[i] = (x0[i]-mu)*rs*gv0[i] + bv0[i];
    y1[i] = (x1[i]-mu)*rs*gv1[i] + bv1[i];
  }
  if (outf){ *(f32x4*)(outf+base) = y0; *(f32x4*)(outf+base+4) = y1; }
  if (outb){
    f32x4 z0 = y0, z1 = y1;
    if (gn){   // second LN (next layer's input-LN) in-register
      float s2 = z0[0]+z0[1]+z0[2]+z0[3]+z1[0]+z1[1]+z1[2]+z1[3];
      #pragma unroll
      for (int m = 1; m < 64; m <<= 1) s2 += __shfl_xor(s2, m, 64);
      const float mu2 = s2 * (1.f/512.f);
      float v2 = 0.f;
      #pragma unroll
      for (int i = 0; i < 4; i++){
        float d0 = z0[i]-mu2; v2 += d0*d0;
        float d1 = z1[i]-mu2; v2 += d1*d1;
      }
      #pragma unroll
      for (int m = 1; m < 64; m <<= 1) v2 += __shfl_xor(v2, m, 64);
      const float rs2 = rsqrtf(v2 * (1.f/512.f) + 1e-3f);
      f32x4 gn0 = *(const f32x4*)(gn+col), gn1 = *(const f32x4*)(gn+col+4);
      f32x4 bn0 = *(const f32x4*)(bn+col), bn1 = *(const f32x4*)(bn+col+4);
      #pragma unroll
      for (int i = 0; i < 4; i++){
        z0[i] = (z0[i]-mu2)*rs2*gn0[i] + bn0[i];
        z1[i] = (z1[i]-mu2)*rs2*gn1[i] + bn1[i];
      }
    }
    bf16x8 ob;
    #pragma unroll
    for (int i = 0; i < 4; i++){ ob[i] = tobf(z0[i]); ob[i+4] = tobf(z1[i]); }
    *(bf16x8*)(outb + base) = ob;
  }
}

// ---------------- ALL weight transposes (4 layers) + initial input-LN --------
__global__ __launch_bounds__(256)
void transpose_all(const float* __restrict__ Wq, const float* __restrict__ Wk,
                   const float* __restrict__ Wv, const float* __restrict__ W1,
                   const float* __restrict__ W2,
                   short* __restrict__ WqkvT, short* __restrict__ W1T,
                   short* __restrict__ W2T,
                   const float* __restrict__ x_in, const float* __restrict__ gin,
                   const float* __restrict__ bin, short* __restrict__ xl)
{
  if (blockIdx.x >= 11264){
    const int row = ((blockIdx.x - 11264) << 2) + (threadIdx.x >> 6);
    ln_row_compute(x_in, nullptr, nullptr, nullptr, gin, bin,
                   nullptr, nullptr, nullptr, xl, row);
    return;
  }
  __shared__ float tsh[32][33];
  const int l = blockIdx.x / 2816;
  const int t = blockIdx.x % 2816;
  const float* src; short* dst; int K, N, local;
  if (t < 768){
    const int m = t >> 8;
    src = (m==0 ? Wq : (m==1 ? Wk : Wv)) + (size_t)l*262144;
    dst = WqkvT + (size_t)l*786432 + m*262144; K = 512; N = 512; local = t & 255;
  } else if (t < 1792){
    src = W1 + (size_t)l*1048576; dst = W1T + (size_t)l*1048576;
    K = 512; N = 2048; local = t - 768;
  } else {
    src = W2 + (size_t)l*1048576; dst = W2T + (size_t)l*1048576;
    K = 2048; N = 512; local = t - 1792;
  }
  const int tnx = N >> 5;
  const int tc = (local % tnx) << 5, tr = (local / tnx) << 5;
  const int lr = threadIdx.x >> 5, lc = threadIdx.x & 31;
  #pragma unroll
  for (int i = 0; i < 32; i += 8)
    tsh[lr + i][lc] = src[(size_t)(tr + lr + i) * N + tc + lc];
  __syncthreads();
  #pragma unroll
  for (int i = 0; i < 32; i += 8)
    dst[(size_t)(tc + lr + i) * K + tr + lc] = tobf(tsh[lc][lr + i]);
}

// ---------------- standalone LN launches -------------------------------------
__global__ __launch_bounds__(256)
void ln_kernel(const float* __restrict__ in, const short* __restrict__ inb,
               const float* __restrict__ resf, const short* __restrict__ resb,
               const float* __restrict__ g, const float* __restrict__ be,
               const float* __restrict__ gn, const float* __restrict__ bn,
               float* __restrict__ outf, short* __restrict__ outb)
{
  const int row = (blockIdx.x << 2) + (threadIdx.x >> 6);
  ln_row_compute(in, inb, resf, resb, g, be, gn, bn, outf, outb, row);
}

// ---------------- bf16 MFMA GEMM, BT input ([N][K]), 64x(32*BJ) tile ---------
// LDS-staged (r7-proven loop), templated BK (64/128/256).
// MODE 0: +bias (3-section), bf16 row-major out, ld=N
// MODE 1: +bias, ReLU, bf16 out, ld=N
template<int MODE, int BJ, int BK>
__global__ __launch_bounds__(256)
void gemm_bt(const short* __restrict__ A, const short* __restrict__ BT,
             int N, int K,
             const float* __restrict__ b0, const float* __restrict__ b1p,
             const float* __restrict__ b2p, void* __restrict__ out0)
{
  constexpr int NTILE = 32*BJ;
  constexpr int UPR = BK/8;           // 16B units per LDS row
  constexpr int AU = 64*UPR/256;      // async16 per thread (A)
  constexpr int BU = NTILE*UPR/256;   // async16 per thread (B)
  __shared__ __align__(16) short Ash[64*BK];
  __shared__ __align__(16) short Bsh[NTILE*BK];
  const int tid = threadIdx.x;
  const int wid = tid >> 6, lane = tid & 63;
  const int l15 = lane & 15, g4 = lane >> 4;
  const int nbn = N / NTILE;
  // bijective XCD-chunk swizzle (gridDim.x % 8 == 0 for all our grids)
  const int cpx = gridDim.x >> 3;
  int bid = blockIdx.x;
  bid = (bid & 7) * cpx + (bid >> 3);
  const int bm = bid / nbn, bn = bid % nbn;
  const int m0 = bm << 6, n0 = bn * NTILE;

  // staging: unit u = 16B; row = u/UPR; physical slot u%UPR holds logical
  // slot (u%UPR)^(row&(UPR-1)) (XOR swizzle, inverted on the read side)
  const short* aP[AU]; const short* bP[BU];
  #pragma unroll
  for (int p = 0; p < AU; p++){
    int u = p*256 + tid, row = u / UPR, sl = (u % UPR) ^ (row & (UPR-1));
    aP[p] = A + (size_t)(m0 + row) * K + sl * 8;
  }
  #pragma unroll
  for (int p = 0; p < BU; p++){
    int u = p*256 + tid, row = u / UPR, sl = (u % UPR) ^ (row & (UPR-1));
    bP[p] = BT + (size_t)(n0 + row) * K + sl * 8;
  }
  char* ldsA = (char*)Ash;
  char* ldsB = (char*)Bsh;

  f32x4 acc[2][BJ] = {};
  const int wr = wid & 1, wc = wid >> 1;
  const int nkt = K / BK;

  for (int kt = 0; kt < nkt; ++kt){
    const int k0 = kt * BK;
    #pragma unroll
    for (int p = 0; p < AU; p++)
      async16(aP[p] + k0, ldsA + (p*256 + wid*64) * 16);
    #pragma unroll
    for (int p = 0; p < BU; p++)
      async16(bP[p] + k0, ldsB + (p*256 + wid*64) * 16);
    __syncthreads();
    #pragma unroll
    for (int ks = 0; ks < BK/32; ++ks){
      bf16x8 af[2], bfm[BJ];
      #pragma unroll
      for (int i = 0; i < 2; i++){
        const int ar = wr*32 + i*16 + l15;
        af[i] = *(const bf16x8*)&ldsA[ar*(2*BK) + (((ks<<2)+g4) ^ (ar&(UPR-1)))*16];
      }
      #pragma unroll
      for (int j = 0; j < BJ; j++){
        const int br = wc*(16*BJ) + j*16 + l15;
        bfm[j] = *(const bf16x8*)&ldsB[br*(2*BK) + (((ks<<2)+g4) ^ (br&(UPR-1)))*16];
      }
      #pragma unroll
      for (int i = 0; i < 2; i++)
        #pragma unroll
        for (int j = 0; j < BJ; j++)
          acc[i][j] = mfma16(af[i], bfm[j], acc[i][j]);
    }
    __syncthreads();
  }

  // epilogue: D layout col=lane&15, row=(lane>>4)*4+reg
  const int r0 = m0 + wr*32 + g4*4;
  const int cc0 = n0 + wc*16*BJ + l15;
  #pragma unroll
  for (int j = 0; j < BJ; j++){
    const int gc = cc0 + j*16;
    if (MODE == 0){
      const float bi = gc < 512 ? b0[gc] : (gc < 1024 ? b1p[gc-512] : b2p[gc-1024]);
      short* ob = (short*)out0;
      #pragma unroll
      for (int i = 0; i < 2; i++)
        #pragma unroll
        for (int r = 0; r < 4; r++){
          const int grow = r0 + i*16 + r;
          ob[(size_t)grow * N + gc] = tobf(acc[i][j][r] + bi);
        }
    } else {
      const float bi = b0[gc];
      short* ob = (short*)out0;
      #pragma unroll
      for (int i = 0; i < 2; i++)
        #pragma unroll
        for (int r = 0; r < 4; r++){
          const int grow = r0 + i*16 + r;
          float v = acc[i][j][r] + bi;
          v = fmaxf(v, 0.f);
          ob[(size_t)grow * N + gc] = tobf(v);
        }
    }
  }
}

// ---------------- unified banded chunk attention (+fused residual add) -------
// qkv row-major [B*S, 1536]: cols 0-511 Q, 512-1023 K, 1024-1535 V
__global__ __launch_bounds__(256)
void attn_kernel(const short* __restrict__ qkv, float* __restrict__ attnO,
                 const float* __restrict__ resid)
{
  constexpr int NT = 14, NK2 = 7, VS = 232, LDQ = 1536;
  __shared__ __align__(16) short Vt[64*VS];
  __shared__ __align__(16) short Pl[4][16*VS];
  const int c = blockIdx.x, h = blockIdx.y, b = blockIdx.z;
  const int kb0 = 64*c - 128;
  const size_t rowbase = (size_t)b*2048;
  const short* Q     = qkv + (rowbase + 64*c)*LDQ + h*64;
  const short* Kbase = qkv + rowbase*LDQ + 512  + h*64;
  const short* Vbase = qkv + rowbase*LDQ + 1024 + h*64;
  const int tid = threadIdx.x, wid = tid >> 6, lane = tid & 63;
  const int l15 = lane & 15, g4 = lane >> 4;

  // stage V transposed: vectorized global load (bf16x8 along d), scalar scatter
  for (int idx = tid; idx < NT*16*8; idx += 256){
    const int t = idx >> 7, rem = idx & 127;
    const int r = rem >> 3, d8 = (rem & 7) << 3;
    const int kb = kb0 + t*16;
    bf16x8 v = {0,0,0,0,0,0,0,0};
    if (kb >= 0 && kb + 16 <= 2048)
      v = *(const bf16x8*)(Vbase + (size_t)(kb + r)*LDQ + d8);
    short* dst = &Vt[d8*VS + t*16 + r];
    #pragma unroll
    for (int e = 0; e < 8; e++) dst[e*VS] = v[e];
  }

  const short* qr = Q + (wid*16 + l15)*LDQ + g4*8;
  const bf16x8 aq0 = *(const bf16x8*)qr;
  const bf16x8 aq1 = *(const bf16x8*)(qr + 32);

  f32x4 sf[NT];
  #pragma unroll
  for (int t = 0; t < NT; t++){
    const int kb = kb0 + t*16;
    if (kb >= 0 && kb + 16 <= 2048){
      const short* kr = Kbase + (size_t)(kb + l15)*LDQ + g4*8;
      const bf16x8 k0 = *(const bf16x8*)kr;
      const bf16x8 k1 = *(const bf16x8*)(kr + 32);
      f32x4 z = {0.f,0.f,0.f,0.f};
      z = mfma16(aq0, k0, z);
      z = mfma16(aq1, k1, z);
      sf[t] = z;
    } else {
      sf[t] = (f32x4){-1e9f,-1e9f,-1e9f,-1e9f};
    }
  }

  float mx[4] = {-1e30f,-1e30f,-1e30f,-1e30f};
  #pragma unroll
  for (int t = 0; t < NT; t++)
    #pragma unroll
    for (int r = 0; r < 4; r++) mx[r] = fmaxf(mx[r], sf[t][r]);
  #pragma unroll
  for (int m = 1; m < 16; m <<= 1)
    #pragma unroll
    for (int r = 0; r < 4; r++) mx[r] = fmaxf(mx[r], __shfl_xor(mx[r], m, 64));

  float sum[4] = {0.f,0.f,0.f,0.f};
  #pragma unroll
  for (int t = 0; t < NT; t++)
    #pragma unroll
    for (int r = 0; r < 4; r++){
      const float p = __expf((sf[t][r] - mx[r]) * 0.125f);
      sf[t][r] = p; sum[r] += p;
    }
  #pragma unroll
  for (int m = 1; m < 16; m <<= 1)
    #pragma unroll
    for (int r = 0; r < 4; r++) sum[r] += __shfl_xor(sum[r], m, 64);
  float inv[4];
  #pragma unroll
  for (int r = 0; r < 4; r++) inv[r] = 1.f / sum[r];

  short* Pw = Pl[wid];
  #pragma unroll
  for (int t = 0; t < NT; t++)
    #pragma unroll
    for (int r = 0; r < 4; r++)
      Pw[(g4*4 + r)*VS + t*16 + l15] = tobf(sf[t][r]);

  __syncthreads();

  f32x4 ao[4] = {};
  #pragma unroll
  for (int ks = 0; ks < NK2; ks++){
    const bf16x8 pa = *(const bf16x8*)&Pw[l15*VS + ks*32 + g4*8];
    #pragma unroll
    for (int ni = 0; ni < 4; ni++){
      const bf16x8 vb = *(const bf16x8*)&Vt[(ni*16 + l15)*VS + ks*32 + g4*8];
      ao[ni] = mfma16(pa, vb, ao[ni]);
    }
  }

  const int orow = 64*c + wid*16 + g4*4;
  const size_t obase = ((size_t)b*2048 + orow)*512 + h*64;
  float* ob = attnO + obase;
  const float* rb = resid + obase;
  #pragma unroll
  for (int ni = 0; ni < 4; ni++)
    #pragma unroll
    for (int r = 0; r < 4; r++)
      ob[(size_t)r*512 + ni*16 + l15] = ao[ni][r] * inv[r] + rb[(size_t)r*512 + ni*16 + l15];
}

// ---------------- host launcher ----------------------------------------------
extern "C" void kernel_launch(void* const* d_in, const int* in_sizes, int n_in,
                              void* d_out, int out_size, void* d_ws, size_t ws_size,
                              hipStream_t stream)
{
  const float* x_in = (const float*)d_in[0];
  const float* Wq = (const float*)d_in[2];
  const float* bq = (const float*)d_in[3];
  const float* Wk = (const float*)d_in[4];
  const float* bk = (const float*)d_in[5];
  const float* Wv = (const float*)d_in[6];
  const float* bv = (const float*)d_in[7];
  const float* W1 = (const float*)d_in[8];
  const float* b1 = (const float*)d_in[9];
  const float* W2 = (const float*)d_in[10];
  const float* b2 = (const float*)d_in[11];
  const float* gin = (const float*)d_in[12];
  const float* bin = (const float*)d_in[13];
  const float* g1  = (const float*)d_in[14];
  const float* be1 = (const float*)d_in[15];
  const float* g2  = (const float*)d_in[16];
  const float* be2 = (const float*)d_in[17];

  char* ws = (char*)d_ws;
  size_t o = 0;
  float* xbuf  = (float*)(ws + o); o += (size_t)4096*512*4;   // layer input x (f32)
  short* xl    = (short*)(ws + o); o += (size_t)4096*512*2;   // bf16 LN output (GEMM A / residual)
  short* qkv   = (short*)(ws + o); o += (size_t)4096*1536*2;  // row-major QKV
  float* attnO = (float*)(ws + o); o += (size_t)4096*512*4;   // attn out + x
  short* h1    = (short*)(ws + o); o += (size_t)4096*2048*2;  // FFN hidden
  short* f2out = (short*)(ws + o); o += (size_t)4096*512*2;   // FFN2 out (bf16, +bias)
  short* WqkvT = (short*)(ws + o); o += (size_t)4*1536*512*2;
  short* W1T   = (short*)(ws + o); o += (size_t)4*2048*512*2;
  short* W2T   = (short*)(ws + o); o += (size_t)4*512*2048*2;

  transpose_all<<<12288,256,0,stream>>>(Wq, Wk, Wv, W1, W2, WqkvT, W1T, W2T,
                                        x_in, gin, bin, xl);

  for (int l = 0; l < 4; l++){
    gemm_bt<0,3,128><<<1024,256,0,stream>>>(xl, WqkvT + (size_t)l*786432, 1536, 512,
                                            bq + l*512, bk + l*512, bv + l*512, qkv);
    attn_kernel<<<dim3(32,8,2),256,0,stream>>>(qkv, attnO, l == 0 ? x_in : xbuf);
    // ln1: xl = bf16 LN(attnO)  (serves as FFN1 input AND ln2 residual)
    ln_kernel<<<1024,256,0,stream>>>(attnO, nullptr, nullptr, nullptr,
                                     g1 + l*512, be1 + l*512, nullptr, nullptr,
                                     nullptr, xl);
    gemm_bt<1,4,128><<<1024,256,0,stream>>>(xl, W1T + (size_t)l*1048576, 2048, 512,
                                            b1 + l*2048, nullptr, nullptr, h1);
    gemm_bt<0,2,256><<<512,256,0,stream>>>(h1, W2T + (size_t)l*1048576, 512, 2048,
                                           b2 + l*512, nullptr, nullptr, f2out);
    if (l < 3){
      ln_kernel<<<1024,256,0,stream>>>(nullptr, f2out, nullptr, xl,
                                       g2 + l*512, be2 + l*512,
                                       gin + (l+1)*512, bin + (l+1)*512,
                                       xbuf, xl);
    } else {
      ln_kernel<<<1024,256,0,stream>>>(nullptr, f2out, nullptr, xl,
                                       g2 + l*512, be2 + l*512,
                                       nullptr, nullptr, (float*)d_out, nullptr);
    }
  }
}

// Round 11
// 285.006 us; speedup vs baseline: 2.6855x; 1.0271x over previous
//
#include <hip/hip_runtime.h>
#include <stdint.h>

#define DEVI __device__ __forceinline__

typedef __attribute__((ext_vector_type(8))) short bf16x8;
typedef __attribute__((ext_vector_type(4))) float f32x4;

DEVI short tobf(float v){
  uint32_t u = __builtin_bit_cast(uint32_t, v);
  uint32_t r = (u + 0x7fffu + ((u >> 16) & 1u)) >> 16;
  return (short)(uint16_t)r;
}

DEVI float frombf(short s){
  uint32_t u = ((uint32_t)(uint16_t)s) << 16;
  return __builtin_bit_cast(float, u);
}

DEVI f32x4 mfma16(bf16x8 a, bf16x8 b, f32x4 c){
  return __builtin_amdgcn_mfma_f32_16x16x32_bf16(a, b, c, 0, 0, 0);
}

DEVI void async16(const void* g, void* lds_uniform){
  __builtin_amdgcn_global_load_lds(
      (const __attribute__((address_space(1))) unsigned int*)g,
      (__attribute__((address_space(3))) unsigned int*)lds_uniform,
      16, 0, 0);
}

// ---------------- shared LN row routine (one wave = one row of 512) ----------
// x = (in | inb) + resf? + resb?(bf16)
DEVI void ln_row_compute(const float* __restrict__ in, const short* __restrict__ inb,
                         const float* __restrict__ resf, const short* __restrict__ resb,
                         const float* __restrict__ g, const float* __restrict__ be,
                         const float* __restrict__ gn, const float* __restrict__ bn,
                         float* __restrict__ outf, short* __restrict__ outb, int row)
{
  const int lane = threadIdx.x & 63;
  const size_t base = (size_t)row * 512 + lane * 8;
  const int col = lane * 8;
  f32x4 x0, x1;
  if (in){
    x0 = *(const f32x4*)(in + base);
    x1 = *(const f32x4*)(in + base + 4);
  } else {
    bf16x8 ib = *(const bf16x8*)(inb + base);
    #pragma unroll
    for (int i = 0; i < 4; i++){ x0[i] = frombf(ib[i]); x1[i] = frombf(ib[i+4]); }
  }
  if (resf){
    f32x4 r0v = *(const f32x4*)(resf + base), r1v = *(const f32x4*)(resf + base + 4);
    x0 += r0v; x1 += r1v;
  }
  if (resb){
    bf16x8 rb = *(const bf16x8*)(resb + base);
    #pragma unroll
    for (int i = 0; i < 4; i++){ x0[i] += frombf(rb[i]); x1[i] += frombf(rb[i+4]); }
  }
  float s = x0[0]+x0[1]+x0[2]+x0[3]+x1[0]+x1[1]+x1[2]+x1[3];
  #pragma unroll
  for (int m = 1; m < 64; m <<= 1) s += __shfl_xor(s, m, 64);
  const float mu = s * (1.f/512.f);
  float vs = 0.f;
  #pragma unroll
  for (int i = 0; i < 4; i++){
    float d0 = x0[i]-mu; vs += d0*d0;
    float d1 = x1[i]-mu; vs += d1*d1;
  }
  #pragma unroll
  for (int m = 1; m < 64; m <<= 1) vs += __shfl_xor(vs, m, 64);
  const float rs = rsqrtf(vs * (1.f/512.f) + 1e-3f);
  f32x4 gv0 = *(const f32x4*)(g+col),  gv1 = *(const f32x4*)(g+col+4);
  f32x4 bv0 = *(const f32x4*)(be+col), bv1 = *(const f32x4*)(be+col+4);
  f32x4 y0, y1;
  #pragma unroll
  for (int i = 0; i < 4; i++){
    y0[i] = (x0[i]-mu)*rs*gv0[i] + bv0[i];
    y1[i] = (x1[i]-mu)*rs*gv1[i] + bv1[i];
  }
  if (outf){ *(f32x4*)(outf+base) = y0; *(f32x4*)(outf+base+4) = y1; }
  if (outb){
    f32x4 z0 = y0, z1 = y1;
    if (gn){   // second LN (next layer's input-LN) in-register
      float s2 = z0[0]+z0[1]+z0[2]+z0[3]+z1[0]+z1[1]+z1[2]+z1[3];
      #pragma unroll
      for (int m = 1; m < 64; m <<= 1) s2 += __shfl_xor(s2, m, 64);
      const float mu2 = s2 * (1.f/512.f);
      float v2 = 0.f;
      #pragma unroll
      for (int i = 0; i < 4; i++){
        float d0 = z0[i]-mu2; v2 += d0*d0;
        float d1 = z1[i]-mu2; v2 += d1*d1;
      }
      #pragma unroll
      for (int m = 1; m < 64; m <<= 1) v2 += __shfl_xor(v2, m, 64);
      const float rs2 = rsqrtf(v2 * (1.f/512.f) + 1e-3f);
      f32x4 gn0 = *(const f32x4*)(gn+col), gn1 = *(const f32x4*)(gn+col+4);
      f32x4 bn0 = *(const f32x4*)(bn+col), bn1 = *(const f32x4*)(bn+col+4);
      #pragma unroll
      for (int i = 0; i < 4; i++){
        z0[i] = (z0[i]-mu2)*rs2*gn0[i] + bn0[i];
        z1[i] = (z1[i]-mu2)*rs2*gn1[i] + bn1[i];
      }
    }
    bf16x8 ob;
    #pragma unroll
    for (int i = 0; i < 4; i++){ ob[i] = tobf(z0[i]); ob[i+4] = tobf(z1[i]); }
    *(bf16x8*)(outb + base) = ob;
  }
}

// ---------------- ALL weight transposes (4 layers) + initial input-LN --------
__global__ __launch_bounds__(256)
void transpose_all(const float* __restrict__ Wq, const float* __restrict__ Wk,
                   const float* __restrict__ Wv, const float* __restrict__ W1,
                   const float* __restrict__ W2,
                   short* __restrict__ WqkvT, short* __restrict__ W1T,
                   short* __restrict__ W2T,
                   const float* __restrict__ x_in, const float* __restrict__ gin,
                   const float* __restrict__ bin, short* __restrict__ xl)
{
  if (blockIdx.x >= 11264){
    const int row = ((blockIdx.x - 11264) << 2) + (threadIdx.x >> 6);
    ln_row_compute(x_in, nullptr, nullptr, nullptr, gin, bin,
                   nullptr, nullptr, nullptr, xl, row);
    return;
  }
  __shared__ float tsh[32][33];
  const int l = blockIdx.x / 2816;
  const int t = blockIdx.x % 2816;
  const float* src; short* dst; int K, N, local;
  if (t < 768){
    const int m = t >> 8;
    src = (m==0 ? Wq : (m==1 ? Wk : Wv)) + (size_t)l*262144;
    dst = WqkvT + (size_t)l*786432 + m*262144; K = 512; N = 512; local = t & 255;
  } else if (t < 1792){
    src = W1 + (size_t)l*1048576; dst = W1T + (size_t)l*1048576;
    K = 512; N = 2048; local = t - 768;
  } else {
    src = W2 + (size_t)l*1048576; dst = W2T + (size_t)l*1048576;
    K = 2048; N = 512; local = t - 1792;
  }
  const int tnx = N >> 5;
  const int tc = (local % tnx) << 5, tr = (local / tnx) << 5;
  const int lr = threadIdx.x >> 5, lc = threadIdx.x & 31;
  #pragma unroll
  for (int i = 0; i < 32; i += 8)
    tsh[lr + i][lc] = src[(size_t)(tr + lr + i) * N + tc + lc];
  __syncthreads();
  #pragma unroll
  for (int i = 0; i < 32; i += 8)
    dst[(size_t)(tc + lr + i) * K + tr + lc] = tobf(tsh[lc][lr + i]);
}

// ---------------- standalone LN launches -------------------------------------
__global__ __launch_bounds__(256)
void ln_kernel(const float* __restrict__ in, const short* __restrict__ inb,
               const float* __restrict__ resf, const short* __restrict__ resb,
               const float* __restrict__ g, const float* __restrict__ be,
               const float* __restrict__ gn, const float* __restrict__ bn,
               float* __restrict__ outf, short* __restrict__ outb)
{
  const int row = (blockIdx.x << 2) + (threadIdx.x >> 6);
  ln_row_compute(in, inb, resf, resb, g, be, gn, bn, outf, outb, row);
}

// ---------------- bf16 MFMA GEMM, BT input ([N][K]), 64x(32*BJ) tile ---------
// LDS-staged (r7-proven loop), templated BK (64/128/256).
// MODE 0: +bias (3-section), bf16 row-major out, ld=N
// MODE 1: +bias, ReLU, bf16 out, ld=N
template<int MODE, int BJ, int BK>
__global__ __launch_bounds__(256)
void gemm_bt(const short* __restrict__ A, const short* __restrict__ BT,
             int N, int K,
             const float* __restrict__ b0, const float* __restrict__ b1p,
             const float* __restrict__ b2p, void* __restrict__ out0)
{
  constexpr int NTILE = 32*BJ;
  constexpr int UPR = BK/8;           // 16B units per LDS row
  constexpr int AU = 64*UPR/256;      // async16 per thread (A)
  constexpr int BU = NTILE*UPR/256;   // async16 per thread (B)
  __shared__ __align__(16) short Ash[64*BK];
  __shared__ __align__(16) short Bsh[NTILE*BK];
  const int tid = threadIdx.x;
  const int wid = tid >> 6, lane = tid & 63;
  const int l15 = lane & 15, g4 = lane >> 4;
  const int nbn = N / NTILE;
  // bijective XCD-chunk swizzle (gridDim.x % 8 == 0 for all our grids)
  const int cpx = gridDim.x >> 3;
  int bid = blockIdx.x;
  bid = (bid & 7) * cpx + (bid >> 3);
  const int bm = bid / nbn, bn = bid % nbn;
  const int m0 = bm << 6, n0 = bn * NTILE;

  // staging: unit u = 16B; row = u/UPR; physical slot u%UPR holds logical
  // slot (u%UPR)^(row&(UPR-1)) (XOR swizzle, inverted on the read side)
  const short* aP[AU]; const short* bP[BU];
  #pragma unroll
  for (int p = 0; p < AU; p++){
    int u = p*256 + tid, row = u / UPR, sl = (u % UPR) ^ (row & (UPR-1));
    aP[p] = A + (size_t)(m0 + row) * K + sl * 8;
  }
  #pragma unroll
  for (int p = 0; p < BU; p++){
    int u = p*256 + tid, row = u / UPR, sl = (u % UPR) ^ (row & (UPR-1));
    bP[p] = BT + (size_t)(n0 + row) * K + sl * 8;
  }
  char* ldsA = (char*)Ash;
  char* ldsB = (char*)Bsh;

  f32x4 acc[2][BJ] = {};
  const int wr = wid & 1, wc = wid >> 1;
  const int nkt = K / BK;

  for (int kt = 0; kt < nkt; ++kt){
    const int k0 = kt * BK;
    #pragma unroll
    for (int p = 0; p < AU; p++)
      async16(aP[p] + k0, ldsA + (p*256 + wid*64) * 16);
    #pragma unroll
    for (int p = 0; p < BU; p++)
      async16(bP[p] + k0, ldsB + (p*256 + wid*64) * 16);
    __syncthreads();
    #pragma unroll
    for (int ks = 0; ks < BK/32; ++ks){
      bf16x8 af[2], bfm[BJ];
      #pragma unroll
      for (int i = 0; i < 2; i++){
        const int ar = wr*32 + i*16 + l15;
        af[i] = *(const bf16x8*)&ldsA[ar*(2*BK) + (((ks<<2)+g4) ^ (ar&(UPR-1)))*16];
      }
      #pragma unroll
      for (int j = 0; j < BJ; j++){
        const int br = wc*(16*BJ) + j*16 + l15;
        bfm[j] = *(const bf16x8*)&ldsB[br*(2*BK) + (((ks<<2)+g4) ^ (br&(UPR-1)))*16];
      }
      #pragma unroll
      for (int i = 0; i < 2; i++)
        #pragma unroll
        for (int j = 0; j < BJ; j++)
          acc[i][j] = mfma16(af[i], bfm[j], acc[i][j]);
    }
    __syncthreads();
  }

  // epilogue: D layout col=lane&15, row=(lane>>4)*4+reg
  const int r0 = m0 + wr*32 + g4*4;
  const int cc0 = n0 + wc*16*BJ + l15;
  #pragma unroll
  for (int j = 0; j < BJ; j++){
    const int gc = cc0 + j*16;
    if (MODE == 0){
      const float bi = gc < 512 ? b0[gc] : (gc < 1024 ? b1p[gc-512] : b2p[gc-1024]);
      short* ob = (short*)out0;
      #pragma unroll
      for (int i = 0; i < 2; i++)
        #pragma unroll
        for (int r = 0; r < 4; r++){
          const int grow = r0 + i*16 + r;
          ob[(size_t)grow * N + gc] = tobf(acc[i][j][r] + bi);
        }
    } else {
      const float bi = b0[gc];
      short* ob = (short*)out0;
      #pragma unroll
      for (int i = 0; i < 2; i++)
        #pragma unroll
        for (int r = 0; r < 4; r++){
          const int grow = r0 + i*16 + r;
          float v = acc[i][j][r] + bi;
          v = fmaxf(v, 0.f);
          ob[(size_t)grow * N + gc] = tobf(v);
        }
    }
  }
}

// ---------------- unified banded chunk attention (+fused residual add) -------
// qkv row-major [B*S, 1536]: cols 0-511 Q, 512-1023 K, 1024-1535 V
// output: bf16 [B*S, 512] = attn + resid(f32)
__global__ __launch_bounds__(256)
void attn_kernel(const short* __restrict__ qkv, short* __restrict__ attnO,
                 const float* __restrict__ resid)
{
  constexpr int NT = 14, NK2 = 7, VS = 232, LDQ = 1536;
  __shared__ __align__(16) short Vt[64*VS];
  __shared__ __align__(16) short Pl[4][16*VS];
  const int c = blockIdx.x, h = blockIdx.y, b = blockIdx.z;
  const int kb0 = 64*c - 128;
  const size_t rowbase = (size_t)b*2048;
  const short* Q     = qkv + (rowbase + 64*c)*LDQ + h*64;
  const short* Kbase = qkv + rowbase*LDQ + 512  + h*64;
  const short* Vbase = qkv + rowbase*LDQ + 1024 + h*64;
  const int tid = threadIdx.x, wid = tid >> 6, lane = tid & 63;
  const int l15 = lane & 15, g4 = lane >> 4;

  // stage V transposed: vectorized global load (bf16x8 along d), scalar scatter
  for (int idx = tid; idx < NT*16*8; idx += 256){
    const int t = idx >> 7, rem = idx & 127;
    const int r = rem >> 3, d8 = (rem & 7) << 3;
    const int kb = kb0 + t*16;
    bf16x8 v = {0,0,0,0,0,0,0,0};
    if (kb >= 0 && kb + 16 <= 2048)
      v = *(const bf16x8*)(Vbase + (size_t)(kb + r)*LDQ + d8);
    short* dst = &Vt[d8*VS + t*16 + r];
    #pragma unroll
    for (int e = 0; e < 8; e++) dst[e*VS] = v[e];
  }

  const short* qr = Q + (wid*16 + l15)*LDQ + g4*8;
  const bf16x8 aq0 = *(const bf16x8*)qr;
  const bf16x8 aq1 = *(const bf16x8*)(qr + 32);

  f32x4 sf[NT];
  #pragma unroll
  for (int t = 0; t < NT; t++){
    const int kb = kb0 + t*16;
    if (kb >= 0 && kb + 16 <= 2048){
      const short* kr = Kbase + (size_t)(kb + l15)*LDQ + g4*8;
      const bf16x8 k0 = *(const bf16x8*)kr;
      const bf16x8 k1 = *(const bf16x8*)(kr + 32);
      f32x4 z = {0.f,0.f,0.f,0.f};
      z = mfma16(aq0, k0, z);
      z = mfma16(aq1, k1, z);
      sf[t] = z;
    } else {
      sf[t] = (f32x4){-1e9f,-1e9f,-1e9f,-1e9f};
    }
  }

  float mx[4] = {-1e30f,-1e30f,-1e30f,-1e30f};
  #pragma unroll
  for (int t = 0; t < NT; t++)
    #pragma unroll
    for (int r = 0; r < 4; r++) mx[r] = fmaxf(mx[r], sf[t][r]);
  #pragma unroll
  for (int m = 1; m < 16; m <<= 1)
    #pragma unroll
    for (int r = 0; r < 4; r++) mx[r] = fmaxf(mx[r], __shfl_xor(mx[r], m, 64));

  float sum[4] = {0.f,0.f,0.f,0.f};
  #pragma unroll
  for (int t = 0; t < NT; t++)
    #pragma unroll
    for (int r = 0; r < 4; r++){
      const float p = __expf((sf[t][r] - mx[r]) * 0.125f);
      sf[t][r] = p; sum[r] += p;
    }
  #pragma unroll
  for (int m = 1; m < 16; m <<= 1)
    #pragma unroll
    for (int r = 0; r < 4; r++) sum[r] += __shfl_xor(sum[r], m, 64);
  float inv[4];
  #pragma unroll
  for (int r = 0; r < 4; r++) inv[r] = 1.f / sum[r];

  short* Pw = Pl[wid];
  #pragma unroll
  for (int t = 0; t < NT; t++)
    #pragma unroll
    for (int r = 0; r < 4; r++)
      Pw[(g4*4 + r)*VS + t*16 + l15] = tobf(sf[t][r]);

  __syncthreads();

  f32x4 ao[4] = {};
  #pragma unroll
  for (int ks = 0; ks < NK2; ks++){
    const bf16x8 pa = *(const bf16x8*)&Pw[l15*VS + ks*32 + g4*8];
    #pragma unroll
    for (int ni = 0; ni < 4; ni++){
      const bf16x8 vb = *(const bf16x8*)&Vt[(ni*16 + l15)*VS + ks*32 + g4*8];
      ao[ni] = mfma16(pa, vb, ao[ni]);
    }
  }

  const int orow = 64*c + wid*16 + g4*4;
  const size_t obase = ((size_t)b*2048 + orow)*512 + h*64;
  short* ob = attnO + obase;
  const float* rb = resid + obase;
  #pragma unroll
  for (int ni = 0; ni < 4; ni++)
    #pragma unroll
    for (int r = 0; r < 4; r++)
      ob[(size_t)r*512 + ni*16 + l15] =
          tobf(ao[ni][r] * inv[r] + rb[(size_t)r*512 + ni*16 + l15]);
}

// ---------------- host launcher ----------------------------------------------
extern "C" void kernel_launch(void* const* d_in, const int* in_sizes, int n_in,
                              void* d_out, int out_size, void* d_ws, size_t ws_size,
                              hipStream_t stream)
{
  const float* x_in = (const float*)d_in[0];
  const float* Wq = (const float*)d_in[2];
  const float* bq = (const float*)d_in[3];
  const float* Wk = (const float*)d_in[4];
  const float* bk = (const float*)d_in[5];
  const float* Wv = (const float*)d_in[6];
  const float* bv = (const float*)d_in[7];
  const float* W1 = (const float*)d_in[8];
  const float* b1 = (const float*)d_in[9];
  const float* W2 = (const float*)d_in[10];
  const float* b2 = (const float*)d_in[11];
  const float* gin = (const float*)d_in[12];
  const float* bin = (const float*)d_in[13];
  const float* g1  = (const float*)d_in[14];
  const float* be1 = (const float*)d_in[15];
  const float* g2  = (const float*)d_in[16];
  const float* be2 = (const float*)d_in[17];

  char* ws = (char*)d_ws;
  size_t o = 0;
  float* xbuf  = (float*)(ws + o); o += (size_t)4096*512*4;   // layer input x (f32 residual)
  short* xl    = (short*)(ws + o); o += (size_t)4096*512*2;   // bf16 LN output (GEMM A / residual)
  short* qkv   = (short*)(ws + o); o += (size_t)4096*1536*2;  // row-major QKV
  short* attnO = (short*)(ws + o); o += (size_t)4096*512*2;   // bf16 attn out + x
  short* h1    = (short*)(ws + o); o += (size_t)4096*2048*2;  // FFN hidden
  short* f2out = (short*)(ws + o); o += (size_t)4096*512*2;   // FFN2 out (bf16, +bias)
  short* WqkvT = (short*)(ws + o); o += (size_t)4*1536*512*2;
  short* W1T   = (short*)(ws + o); o += (size_t)4*2048*512*2;
  short* W2T   = (short*)(ws + o); o += (size_t)4*512*2048*2;

  transpose_all<<<12288,256,0,stream>>>(Wq, Wk, Wv, W1, W2, WqkvT, W1T, W2T,
                                        x_in, gin, bin, xl);

  for (int l = 0; l < 4; l++){
    gemm_bt<0,3,128><<<1024,256,0,stream>>>(xl, WqkvT + (size_t)l*786432, 1536, 512,
                                            bq + l*512, bk + l*512, bv + l*512, qkv);
    attn_kernel<<<dim3(32,8,2),256,0,stream>>>(qkv, attnO, l == 0 ? x_in : xbuf);
    // ln1: xl = bf16 LN(attnO)  (serves as FFN1 input AND ln2 residual)
    ln_kernel<<<1024,256,0,stream>>>(nullptr, attnO, nullptr, nullptr,
                                     g1 + l*512, be1 + l*512, nullptr, nullptr,
                                     nullptr, xl);
    gemm_bt<1,4,64><<<1024,256,0,stream>>>(xl, W1T + (size_t)l*1048576, 2048, 512,
                                           b1 + l*2048, nullptr, nullptr, h1);
    gemm_bt<0,2,256><<<512,256,0,stream>>>(h1, W2T + (size_t)l*1048576, 512, 2048,
                                           b2 + l*512, nullptr, nullptr, f2out);
    if (l < 3){
      ln_kernel<<<1024,256,0,stream>>>(nullptr, f2out, nullptr, xl,
                                       g2 + l*512, be2 + l*512,
                                       gin + (l+1)*512, bin + (l+1)*512,
                                       xbuf, xl);
    } else {
      ln_kernel<<<1024,256,0,stream>>>(nullptr, f2out, nullptr, xl,
                                       g2 + l*512, be2 + l*512,
                                       nullptr, nullptr, (float*)d_out, nullptr);
    }
  }
}